// Round 11
// baseline (583.884 us; speedup 1.0000x reference)
//
#include <hip/hip_runtime.h>
#include <math.h>

#define NN 100000
#define NE 1600000
#define ETOT (NE + NN)
#define HEADS 8
#define NCLS 40
#define SLOPE 0.2f
#define NREP 8   // atomic counter replicas

#define SCAN_B 512
#define NBLK ((NN + SCAN_B - 1) / SCAN_B)   // 196

typedef unsigned short ushort_t;
typedef __attribute__((ext_vector_type(8))) short short8;
typedef __attribute__((ext_vector_type(8))) _Float16 half8;
typedef __attribute__((ext_vector_type(4))) float f32x4;

static __device__ __forceinline__ ushort_t f2bf(float f) {
    unsigned u = __float_as_uint(f);
    unsigned r = (u + 0x7FFFu + ((u >> 16) & 1u)) >> 16;   // RNE
    return (ushort_t)r;
}
static __device__ __forceinline__ float bf2f(ushort_t b) {
    return __uint_as_float(((unsigned)b) << 16);
}
static __device__ __forceinline__ ushort_t f2h(float f) {
    _Float16 h = (_Float16)f;
    return __builtin_bit_cast(ushort_t, h);
}
static __device__ __forceinline__ float h2f(ushort_t u) {
    return (float)__builtin_bit_cast(_Float16, u);
}

// ----------------- CSR build (8-replica counters) -----------------
__global__ void k_init0(int* __restrict__ p, int n) {
    int i = blockIdx.x * blockDim.x + threadIdx.x;
    if (i < n) p[i] = 0;
}

__global__ void k_hist(const int* __restrict__ ei, int* __restrict__ deg_r) {
    int base = blockIdx.x * 1024 + threadIdx.x;
    int r = threadIdx.x & (NREP - 1);
#pragma unroll
    for (int i = 0; i < 4; i++) {
        int e = base + i * 256;
        if (e < NE) {
            unsigned d = (unsigned)ei[NE + e];
            if (d < NN) atomicAdd(&deg_r[r * NN + (int)d], 1);
        }
    }
}

__global__ void k_blocksum(const int* __restrict__ deg_r, int* __restrict__ degt,
                           int* __restrict__ bsum) {
    __shared__ int sh[SCAN_B];
    int b = blockIdx.x;
    int i = b * SCAN_B + threadIdx.x;
    int tot = 0;
    if (i < NN) {
        tot = 1;  // self loop
#pragma unroll
        for (int r = 0; r < NREP; r++) tot += deg_r[r * NN + i];
        degt[i] = tot;
    }
    sh[threadIdx.x] = tot;
    __syncthreads();
    for (int s = SCAN_B / 2; s > 0; s >>= 1) {
        if (threadIdx.x < s) sh[threadIdx.x] += sh[threadIdx.x + s];
        __syncthreads();
    }
    if (threadIdx.x == 0) bsum[b] = sh[0];
}

__global__ void k_scan_bsums(int* __restrict__ bsum, int nblk) {
    __shared__ int sh[1024];
    int t = threadIdx.x;
    int v = (t < nblk) ? bsum[t] : 0;
    sh[t] = v;
    __syncthreads();
    for (int o = 1; o < 1024; o <<= 1) {
        int add = (t >= o) ? sh[t - o] : 0;
        __syncthreads();
        sh[t] += add;
        __syncthreads();
    }
    if (t < nblk) bsum[t] = sh[t] - v;  // exclusive
}

__global__ void k_offsets(const int* __restrict__ deg_r, const int* __restrict__ degt,
                          const int* __restrict__ bsum, int* __restrict__ offset,
                          int* __restrict__ cur_r, int* __restrict__ csr_src) {
    __shared__ int sh[SCAN_B];
    int b = blockIdx.x, t = threadIdx.x;
    int i = b * SCAN_B + t;
    int v = (i < NN) ? degt[i] : 0;
    sh[t] = v;
    __syncthreads();
    for (int o = 1; o < SCAN_B; o <<= 1) {
        int add = (t >= o) ? sh[t - o] : 0;
        __syncthreads();
        sh[t] += add;
        __syncthreads();
    }
    if (i < NN) {
        int excl = sh[t] - v + bsum[b];
        offset[i] = excl;
        csr_src[excl] = i;  // pre-place self loop
        int c = excl + 1;
#pragma unroll
        for (int r = 0; r < NREP; r++) {
            cur_r[r * NN + i] = c;
            c += deg_r[r * NN + i];
        }
    }
}

__global__ void k_scatter(const int* __restrict__ ei, int* __restrict__ cur_r,
                          int* __restrict__ csr_src) {
    int base = blockIdx.x * 1024 + threadIdx.x;
    int r = threadIdx.x & (NREP - 1);
#pragma unroll
    for (int i = 0; i < 4; i++) {
        int e = base + i * 256;
        if (e < NE) {
            unsigned d = (unsigned)ei[NE + e];
            unsigned s = (unsigned)ei[e];
            if (d < NN && s < NN) {
                int pos = atomicAdd(&cur_r[r * NN + (int)d], 1);
                csr_src[pos] = (int)s;
            }
        }
    }
}

// ------- split W1 (bf16 hi/lo, [n][k]) + W2 (f16 hi/lo, padded [48][256]) --
__global__ void k_splitW(const float* __restrict__ W1, ushort_t* __restrict__ W1ht,
                         ushort_t* __restrict__ W1lt, const float* __restrict__ W2,
                         ushort_t* __restrict__ W2ht, ushort_t* __restrict__ W2lt) {
    if (blockIdx.x < 256) {
        int k = blockIdx.x, n = threadIdx.x;
        float v = W1[k * 256 + n];
        ushort_t hi = f2bf(v);
        ushort_t lo = f2bf(v - bf2f(hi));
        W1ht[n * 256 + k] = hi;
        W1lt[n * 256 + k] = lo;
    } else {
        int n = blockIdx.x - 256, k = threadIdx.x;
        float v = (n < NCLS) ? W2[k * NCLS + n] : 0.f;
        ushort_t hi = f2h(v);
        ushort_t lo = f2h(v - h2f(hi));
        W2ht[n * 256 + k] = hi;
        W2lt[n * 256 + k] = lo;
    }
}

// ----------------- GEMM1 (MFMA split-bf16): h1h(f16) = x @ W1; fused alphas
#define LSTR 40   // ushorts per LDS row
__global__ __launch_bounds__(256) void k_gemm1(const float* __restrict__ A,
                                               const ushort_t* __restrict__ Bht,
                                               const ushort_t* __restrict__ Blt,
                                               const float* __restrict__ attS,
                                               const float* __restrict__ attD,
                                               ushort_t* __restrict__ h1h,
                                               float* __restrict__ as1,
                                               float* __restrict__ ad1) {
    __shared__ ushort_t Ah[128 * LSTR];
    __shared__ ushort_t Al[128 * LSTR];
    __shared__ ushort_t Bh[128 * LSTR];
    __shared__ ushort_t Bl[128 * LSTR];

    int bx = blockIdx.x & 1;
    int by = blockIdx.x >> 1;
    int row0 = by * 128, col0 = bx * 128;
    int t = threadIdx.x;
    int w = t >> 6, lane = t & 63;
    int lr = lane & 15, lg = lane >> 4;
    int R0 = (w >> 1) * 64, C0 = (w & 1) * 64;

    int ar = t >> 1, ah = t & 1;          // A: row, k-half(16 f32)
    int gr_a = row0 + ar;

    f32x4 acc[4][4];
#pragma unroll
    for (int i = 0; i < 4; i++)
#pragma unroll
        for (int j = 0; j < 4; j++) acc[i][j] = (f32x4){0.f, 0.f, 0.f, 0.f};

    for (int it = 0; it < 8; it++) {
        int k0 = it * 32;
        __syncthreads();
        // ---- stage A (convert f32 -> bf16 hi/lo) ----
        {
            float f[16];
            if (gr_a < NN) {
                const float* ap = A + (size_t)gr_a * 256 + k0 + ah * 16;
#pragma unroll
                for (int i = 0; i < 4; i++) {
                    float4 v = *reinterpret_cast<const float4*>(ap + i * 4);
                    f[i * 4 + 0] = v.x; f[i * 4 + 1] = v.y; f[i * 4 + 2] = v.z; f[i * 4 + 3] = v.w;
                }
            } else {
#pragma unroll
                for (int i = 0; i < 16; i++) f[i] = 0.f;
            }
            unsigned hw[8], lw[8];
#pragma unroll
            for (int i = 0; i < 8; i++) {
                ushort_t h0 = f2bf(f[2 * i]), h1v = f2bf(f[2 * i + 1]);
                ushort_t l0 = f2bf(f[2 * i] - bf2f(h0)), l1 = f2bf(f[2 * i + 1] - bf2f(h1v));
                hw[i] = (unsigned)h0 | ((unsigned)h1v << 16);
                lw[i] = (unsigned)l0 | ((unsigned)l1 << 16);
            }
            uint4* dsth = reinterpret_cast<uint4*>(&Ah[ar * LSTR + ah * 16]);
            dsth[0] = make_uint4(hw[0], hw[1], hw[2], hw[3]);
            dsth[1] = make_uint4(hw[4], hw[5], hw[6], hw[7]);
            uint4* dstl = reinterpret_cast<uint4*>(&Al[ar * LSTR + ah * 16]);
            dstl[0] = make_uint4(lw[0], lw[1], lw[2], lw[3]);
            dstl[1] = make_uint4(lw[4], lw[5], lw[6], lw[7]);
        }
        // ---- stage B (pre-split, pre-transposed [n][k]) ----
        {
            int bn = t >> 1, bh2 = t & 1;
            const uint4* sh = reinterpret_cast<const uint4*>(Bht + (size_t)(col0 + bn) * 256 + k0 + bh2 * 16);
            const uint4* sl = reinterpret_cast<const uint4*>(Blt + (size_t)(col0 + bn) * 256 + k0 + bh2 * 16);
            uint4* dh = reinterpret_cast<uint4*>(&Bh[bn * LSTR + bh2 * 16]);
            uint4* dl = reinterpret_cast<uint4*>(&Bl[bn * LSTR + bh2 * 16]);
            dh[0] = sh[0]; dh[1] = sh[1];
            dl[0] = sl[0]; dl[1] = sl[1];
        }
        __syncthreads();
        // ---- fragments + MFMA ----
        short8 bhf[4], blf[4];
#pragma unroll
        for (int ni = 0; ni < 4; ni++) {
            int c = C0 + ni * 16 + lr;
            bhf[ni] = *reinterpret_cast<const short8*>(&Bh[c * LSTR + lg * 8]);
            blf[ni] = *reinterpret_cast<const short8*>(&Bl[c * LSTR + lg * 8]);
        }
#pragma unroll
        for (int mi = 0; mi < 4; mi++) {
            int r = R0 + mi * 16 + lr;
            short8 ahf = *reinterpret_cast<const short8*>(&Ah[r * LSTR + lg * 8]);
            short8 alf = *reinterpret_cast<const short8*>(&Al[r * LSTR + lg * 8]);
#pragma unroll
            for (int ni = 0; ni < 4; ni++) {
                acc[mi][ni] = __builtin_amdgcn_mfma_f32_16x16x32_bf16(ahf, bhf[ni], acc[mi][ni], 0, 0, 0);
                acc[mi][ni] = __builtin_amdgcn_mfma_f32_16x16x32_bf16(alf, bhf[ni], acc[mi][ni], 0, 0, 0);
                acc[mi][ni] = __builtin_amdgcn_mfma_f32_16x16x32_bf16(ahf, blf[ni], acc[mi][ni], 0, 0, 0);
            }
        }
    }

    // ---- epilogue: f16 store + fused alpha dots ----
    int cn[4];
    float sa[4], da[4];
#pragma unroll
    for (int ni = 0; ni < 4; ni++) {
        cn[ni] = col0 + C0 + ni * 16 + lr;
        sa[ni] = attS[cn[ni]];
        da[ni] = attD[cn[ni]];
    }
    int head0 = (col0 + C0) >> 5;
#pragma unroll
    for (int mi = 0; mi < 4; mi++) {
#pragma unroll
        for (int r = 0; r < 4; r++) {
            int gr = row0 + R0 + mi * 16 + lg * 4 + r;
            float v0 = acc[mi][0][r], v1 = acc[mi][1][r];
            float v2 = acc[mi][2][r], v3 = acc[mi][3][r];
            float ps0 = v0 * sa[0] + v1 * sa[1];
            float pd0 = v0 * da[0] + v1 * da[1];
            float ps1 = v2 * sa[2] + v3 * sa[3];
            float pd1 = v2 * da[2] + v3 * da[3];
#pragma unroll
            for (int m = 1; m <= 8; m <<= 1) {
                ps0 += __shfl_xor(ps0, m);
                pd0 += __shfl_xor(pd0, m);
                ps1 += __shfl_xor(ps1, m);
                pd1 += __shfl_xor(pd1, m);
            }
            if (gr < NN) {
                if (lr == 0) {
                    as1[gr * 8 + head0] = ps0;
                    ad1[gr * 8 + head0] = pd0;
                    as1[gr * 8 + head0 + 1] = ps1;
                    ad1[gr * 8 + head0 + 1] = pd1;
                }
                ushort_t* hp = h1h + (size_t)gr * 256;
                hp[cn[0]] = f2h(v0);
                hp[cn[1]] = f2h(v1);
                hp[cn[2]] = f2h(v2);
                hp[cn[3]] = f2h(v3);
            }
        }
    }
}

// ------- softmax stats + f16 weight write, layer 1: one wave/node ----------
__global__ __launch_bounds__(256) void k_soft1(const int* __restrict__ csr_src,
                                               const int* __restrict__ offset,
                                               const int* __restrict__ degt,
                                               const float* __restrict__ as1,
                                               const float* __restrict__ ad1,
                                               ushort_t* __restrict__ w1h) {
    int wave = (blockIdx.x * blockDim.x + threadIdx.x) >> 6;
    int lane = threadIdx.x & 63;
    if (wave >= NN) return;
    int d = wave;
    int sub = lane >> 3, h = lane & 7;
    float ad = ad1[d * 8 + h];
    int beg = offset[d], cnt = degt[d];
    float m = -1e30f, s = 0.f;
    for (int j = sub; j < cnt; j += 8) {
        int src = csr_src[beg + j];
        float e = as1[src * 8 + h] + ad;
        e = (e > 0.f) ? e : SLOPE * e;
        float mn = fmaxf(m, e);
        s = s * __expf(m - mn) + __expf(e - mn);
        m = mn;
    }
#pragma unroll
    for (int mask = 8; mask <= 32; mask <<= 1) {
        float mo = __shfl_xor(m, mask);
        float so = __shfl_xor(s, mask);
        float mn = fmaxf(m, mo);
        s = s * __expf(m - mn) + so * __expf(mo - mn);
        m = mn;
    }
    float di = 1.f / (s + 1e-16f);
    // phase 2: write normalized f16 weights, CSR order
    for (int j = sub; j < cnt; j += 8) {
        int src = csr_src[beg + j];
        float e = as1[src * 8 + h] + ad;
        e = (e > 0.f) ? e : SLOPE * e;
        w1h[(size_t)(beg + j) * 8 + h] = f2h(__expf(e - m) * di);
    }
}

// ------- aggregate pass, layer 1: 2 waves/node (feature halves),
//         4 edge slots x 16 feature lanes per wave ---------------------------
__global__ __launch_bounds__(256) void k_agg1(const int* __restrict__ csr_src,
                                              const int* __restrict__ offset,
                                              const int* __restrict__ degt,
                                              const ushort_t* __restrict__ h1h,
                                              const ushort_t* __restrict__ w1h,
                                              const float* __restrict__ bias1,
                                              ushort_t* __restrict__ h2h) {
    int wid = (blockIdx.x * blockDim.x + threadIdx.x) >> 6;
    int lane = threadIdx.x & 63;
    int d = wid >> 1;
    if (d >= NN) return;
    int fh = wid & 1;            // feature half (0: cols 0-127, 1: 128-255)
    int es = lane >> 4;          // edge slot 0..3
    int fl = lane & 15;          // feature lane (8 cols each)
    int f0 = fh * 128 + fl * 8;
    int h = (fh << 2) + (fl >> 2);   // head of these 8 cols
    int beg = offset[d], cnt = degt[d];
    float a[8] = {};
    for (int j0 = 0; j0 < cnt; j0 += 4) {
        int j = j0 + es;
        if (j < cnt) {
            int s = csr_src[beg + j];
            float wg = h2f(w1h[(size_t)(beg + j) * 8 + h]);
            uint4 v = *reinterpret_cast<const uint4*>(h1h + (size_t)s * 256 + f0);
            a[0] += wg * h2f((ushort_t)(v.x & 0xFFFFu));
            a[1] += wg * h2f((ushort_t)(v.x >> 16));
            a[2] += wg * h2f((ushort_t)(v.y & 0xFFFFu));
            a[3] += wg * h2f((ushort_t)(v.y >> 16));
            a[4] += wg * h2f((ushort_t)(v.z & 0xFFFFu));
            a[5] += wg * h2f((ushort_t)(v.z >> 16));
            a[6] += wg * h2f((ushort_t)(v.w & 0xFFFFu));
            a[7] += wg * h2f((ushort_t)(v.w >> 16));
        }
    }
#pragma unroll
    for (int i = 0; i < 8; i++) {
        a[i] += __shfl_xor(a[i], 16);
        a[i] += __shfl_xor(a[i], 32);
    }
    if (es == 0) {
        float4 b0 = *reinterpret_cast<const float4*>(bias1 + f0);
        float4 b1 = *reinterpret_cast<const float4*>(bias1 + f0 + 4);
        float vv[8];
        vv[0] = a[0] + b0.x; vv[1] = a[1] + b0.y; vv[2] = a[2] + b0.z; vv[3] = a[3] + b0.w;
        vv[4] = a[4] + b1.x; vv[5] = a[5] + b1.y; vv[6] = a[6] + b1.z; vv[7] = a[7] + b1.w;
        unsigned p[8];
#pragma unroll
        for (int i = 0; i < 8; i++) {
            float e = (vv[i] > 0.f) ? vv[i] : expm1f(vv[i]);
            p[i] = (unsigned)f2h(e);
        }
        uint4 o;
        o.x = p[0] | (p[1] << 16);
        o.y = p[2] | (p[3] << 16);
        o.z = p[4] | (p[5] << 16);
        o.w = p[6] | (p[7] << 16);
        *reinterpret_cast<uint4*>(h2h + (size_t)d * 256 + f0) = o;
    }
}

// ----------------- GEMM2 (MFMA f16): hh(f16) = h2h @ W2; fused alpha2 ------
__global__ __launch_bounds__(256) void k_gemm2(const ushort_t* __restrict__ A,
                                               const ushort_t* __restrict__ Bht,
                                               const ushort_t* __restrict__ Blt,
                                               const float* __restrict__ attS,
                                               const float* __restrict__ attD,
                                               ushort_t* __restrict__ hh,
                                               float* __restrict__ as2,
                                               float* __restrict__ ad2) {
    __shared__ ushort_t Ash[128 * LSTR];
    __shared__ ushort_t Bh[48 * LSTR];
    __shared__ ushort_t Bl[48 * LSTR];
    int row0 = blockIdx.x * 128;
    int t = threadIdx.x;
    int w = t >> 6, lane = t & 63;
    int lr = lane & 15, lg = lane >> 4;
    int R0 = w * 32;

    f32x4 acc[2][3];
#pragma unroll
    for (int i = 0; i < 2; i++)
#pragma unroll
        for (int j = 0; j < 3; j++) acc[i][j] = (f32x4){0.f, 0.f, 0.f, 0.f};

    for (int it = 0; it < 8; it++) {
        int k0 = it * 32;
        __syncthreads();
        // stage A: 128 rows x 32 ushorts = 512 uint4 chunks
#pragma unroll
        for (int i = 0; i < 2; i++) {
            int chunk = t + i * 256;
            int r = chunk >> 2, part = chunk & 3;
            int gr = row0 + r;
            uint4 v = make_uint4(0u, 0u, 0u, 0u);
            if (gr < NN) v = *reinterpret_cast<const uint4*>(A + (size_t)gr * 256 + k0 + part * 8);
            *reinterpret_cast<uint4*>(&Ash[r * LSTR + part * 8]) = v;
        }
        // stage B: 48 rows x 32 ushorts = 192 uint4 chunks
        if (t < 192) {
            int bn = t >> 2, part = t & 3;
            *reinterpret_cast<uint4*>(&Bh[bn * LSTR + part * 8]) =
                *reinterpret_cast<const uint4*>(Bht + (size_t)bn * 256 + k0 + part * 8);
            *reinterpret_cast<uint4*>(&Bl[bn * LSTR + part * 8]) =
                *reinterpret_cast<const uint4*>(Blt + (size_t)bn * 256 + k0 + part * 8);
        }
        __syncthreads();
        half8 bhf[3], blf[3];
#pragma unroll
        for (int ni = 0; ni < 3; ni++) {
            int c = ni * 16 + lr;
            bhf[ni] = *reinterpret_cast<const half8*>(&Bh[c * LSTR + lg * 8]);
            blf[ni] = *reinterpret_cast<const half8*>(&Bl[c * LSTR + lg * 8]);
        }
#pragma unroll
        for (int mi = 0; mi < 2; mi++) {
            int r = R0 + mi * 16 + lr;
            half8 af = *reinterpret_cast<const half8*>(&Ash[r * LSTR + lg * 8]);
#pragma unroll
            for (int ni = 0; ni < 3; ni++) {
                acc[mi][ni] = __builtin_amdgcn_mfma_f32_16x16x32_f16(af, bhf[ni], acc[mi][ni], 0, 0, 0);
                acc[mi][ni] = __builtin_amdgcn_mfma_f32_16x16x32_f16(af, blf[ni], acc[mi][ni], 0, 0, 0);
            }
        }
    }

    // epilogue: store hh(f16) + fused alpha2
    int cn[3];
    float sa[3], da[3];
#pragma unroll
    for (int ni = 0; ni < 3; ni++) {
        cn[ni] = ni * 16 + lr;
        sa[ni] = (cn[ni] < NCLS) ? attS[cn[ni]] : 0.f;
        da[ni] = (cn[ni] < NCLS) ? attD[cn[ni]] : 0.f;
    }
#pragma unroll
    for (int mi = 0; mi < 2; mi++) {
#pragma unroll
        for (int r = 0; r < 4; r++) {
            int gr = row0 + R0 + mi * 16 + lg * 4 + r;
            float v0 = acc[mi][0][r], v1 = acc[mi][1][r], v2 = acc[mi][2][r];
            float ps = v0 * sa[0] + v1 * sa[1] + v2 * sa[2];
            float pd = v0 * da[0] + v1 * da[1] + v2 * da[2];
#pragma unroll
            for (int m = 1; m <= 8; m <<= 1) {
                ps += __shfl_xor(ps, m);
                pd += __shfl_xor(pd, m);
            }
            if (gr < NN) {
                if (lr == 0) { as2[gr] = ps; ad2[gr] = pd; }
                ushort_t* hp = hh + (size_t)gr * NCLS;
                if (cn[0] < NCLS) hp[cn[0]] = f2h(v0);
                if (cn[1] < NCLS) hp[cn[1]] = f2h(v1);
                if (cn[2] < NCLS) hp[cn[2]] = f2h(v2);
            }
        }
    }
}

// ------- softmax stats + f16 weight write, layer 2: one wave/node ----------
__global__ __launch_bounds__(256) void k_soft2(const int* __restrict__ csr_src,
                                               const int* __restrict__ offset,
                                               const int* __restrict__ degt,
                                               const float* __restrict__ as2,
                                               const float* __restrict__ ad2,
                                               ushort_t* __restrict__ w2h) {
    int wave = (blockIdx.x * blockDim.x + threadIdx.x) >> 6;
    int lane = threadIdx.x & 63;
    if (wave >= NN) return;
    int d = wave;
    float ad = ad2[d];
    int beg = offset[d], cnt = degt[d];
    float m = -1e30f, s = 0.f;
    for (int j = lane; j < cnt; j += 64) {
        int src = csr_src[beg + j];
        float e = as2[src] + ad;
        e = (e > 0.f) ? e : SLOPE * e;
        float mn = fmaxf(m, e);
        s = s * __expf(m - mn) + __expf(e - mn);
        m = mn;
    }
#pragma unroll
    for (int mask = 1; mask <= 32; mask <<= 1) {
        float mo = __shfl_xor(m, mask);
        float so = __shfl_xor(s, mask);
        float mn = fmaxf(m, mo);
        s = s * __expf(m - mn) + so * __expf(mo - mn);
        m = mn;
    }
    float di = 1.f / (s + 1e-16f);
    for (int j = lane; j < cnt; j += 64) {
        int src = csr_src[beg + j];
        float e = as2[src] + ad;
        e = (e > 0.f) ? e : SLOPE * e;
        w2h[beg + j] = f2h(__expf(e - m) * di);
    }
}

// ------- aggregate pass, layer 2: 3 edges in flight, 20 lanes each ---------
__global__ __launch_bounds__(256) void k_agg2(const int* __restrict__ csr_src,
                                              const int* __restrict__ offset,
                                              const int* __restrict__ degt,
                                              const ushort_t* __restrict__ hh,
                                              const ushort_t* __restrict__ w2h,
                                              const float* __restrict__ bias2,
                                              float* __restrict__ out) {
    int wave = (blockIdx.x * blockDim.x + threadIdx.x) >> 6;
    int lane = threadIdx.x & 63;
    if (wave >= NN) return;
    int d = wave;
    int es = lane / 20;       // edge slot 0..2 (3 = idle)
    int ch = lane % 20;       // uint chunk -> classes 2ch, 2ch+1
    int beg = offset[d], cnt = degt[d];
    float a0 = 0.f, a1 = 0.f;
    for (int j0 = 0; j0 < cnt; j0 += 3) {
        int j = j0 + es;
        if (es < 3 && j < cnt) {
            int s = csr_src[beg + j];
            float w = h2f(w2h[beg + j]);
            unsigned v = *reinterpret_cast<const unsigned*>(hh + (size_t)s * NCLS + ch * 2);
            a0 += w * (float)__builtin_bit_cast(_Float16, (ushort_t)(v & 0xFFFFu));
            a1 += w * (float)__builtin_bit_cast(_Float16, (ushort_t)(v >> 16));
        }
    }
    float t0 = __shfl(a0, lane + 20);
    float t1 = __shfl(a0, lane + 40);
    float u0 = __shfl(a1, lane + 20);
    float u1 = __shfl(a1, lane + 40);
    if (lane < 20) {
        float2 o;
        o.x = a0 + t0 + t1 + bias2[ch * 2];
        o.y = a1 + u0 + u1 + bias2[ch * 2 + 1];
        *reinterpret_cast<float2*>(out + (size_t)d * NCLS + ch * 2) = o;
    }
}

extern "C" void kernel_launch(void* const* d_in, const int* in_sizes, int n_in,
                              void* d_out, int out_size, void* d_ws, size_t ws_size,
                              hipStream_t stream) {
    const float* x      = (const float*)d_in[0];
    const int* ei       = (const int*)d_in[1];   // int64 in ref -> int32 on device
    const float* W1     = (const float*)d_in[2];
    const float* att_s1 = (const float*)d_in[3];
    const float* att_d1 = (const float*)d_in[4];
    const float* bias1  = (const float*)d_in[5];
    const float* W2     = (const float*)d_in[6];
    const float* att_s2 = (const float*)d_in[7];
    const float* att_d2 = (const float*)d_in[8];
    const float* bias2  = (const float*)d_in[9];
    float* out = (float*)d_out;

    char* ws = (char*)d_ws;
    size_t off = 0;
    auto alloc = [&](size_t bytes) -> void* {
        void* p = ws + off;
        off = (off + bytes + 255) & ~(size_t)255;
        return p;
    };
    ushort_t* h1h = (ushort_t*)alloc((size_t)NN * 256 * 2);
    ushort_t* h2h = (ushort_t*)alloc((size_t)NN * 256 * 2);
    ushort_t* hh  = (ushort_t*)alloc((size_t)NN * NCLS * 2);
    float* as1  = (float*)alloc((size_t)NN * 8 * 4);
    float* ad1  = (float*)alloc((size_t)NN * 8 * 4);
    float* as2  = (float*)alloc((size_t)NN * 4);
    float* ad2  = (float*)alloc((size_t)NN * 4);
    ushort_t* w1h = (ushort_t*)alloc((size_t)ETOT * 8 * 2);
    ushort_t* w2h = (ushort_t*)alloc((size_t)ETOT * 2);
    int* deg_r  = (int*)alloc((size_t)NN * NREP * 4);
    int* cur_r  = (int*)alloc((size_t)NN * NREP * 4);
    int* degt   = (int*)alloc((size_t)NN * 4);
    int* offs   = (int*)alloc((size_t)(NN + 1) * 4);
    int* csr    = (int*)alloc((size_t)ETOT * 4);
    int* bsum   = (int*)alloc(4096);
    ushort_t* W1ht = (ushort_t*)alloc((size_t)256 * 256 * 2);
    ushort_t* W1lt = (ushort_t*)alloc((size_t)256 * 256 * 2);
    ushort_t* W2ht = (ushort_t*)alloc((size_t)48 * 256 * 2);
    ushort_t* W2lt = (ushort_t*)alloc((size_t)48 * 256 * 2);

    // CSR build with 8-replica counters
    k_init0<<<(NN * NREP + 255) / 256, 256, 0, stream>>>(deg_r, NN * NREP);
    k_hist<<<(NE + 1023) / 1024, 256, 0, stream>>>(ei, deg_r);
    k_blocksum<<<NBLK, SCAN_B, 0, stream>>>(deg_r, degt, bsum);
    k_scan_bsums<<<1, 1024, 0, stream>>>(bsum, NBLK);
    k_offsets<<<NBLK, SCAN_B, 0, stream>>>(deg_r, degt, bsum, offs, cur_r, csr);
    k_scatter<<<(NE + 1023) / 1024, 256, 0, stream>>>(ei, cur_r, csr);

    // Layer 1
    k_splitW<<<304, 256, 0, stream>>>(W1, W1ht, W1lt, W2, W2ht, W2lt);
    k_gemm1<<<((NN + 127) / 128) * 2, 256, 0, stream>>>(x, W1ht, W1lt, att_s1, att_d1, h1h, as1, ad1);
    k_soft1<<<(NN + 3) / 4, 256, 0, stream>>>(csr, offs, degt, as1, ad1, w1h);
    k_agg1<<<(NN * 2 + 3) / 4, 256, 0, stream>>>(csr, offs, degt, h1h, w1h, bias1, h2h);

    // Layer 2
    k_gemm2<<<(NN + 127) / 128, 256, 0, stream>>>(h2h, W2ht, W2lt, att_s2, att_d2, hh, as2, ad2);
    k_soft2<<<(NN + 3) / 4, 256, 0, stream>>>(csr, offs, degt, as2, ad2, w2h);
    k_agg2<<<(NN + 3) / 4, 256, 0, stream>>>(csr, offs, degt, hh, w2h, bias2, out);
}

// Round 12
// 518.341 us; speedup vs baseline: 1.1264x; 1.1264x over previous
//
#include <hip/hip_runtime.h>
#include <math.h>

#define NN 100000
#define NE 1600000
#define ETOT (NE + NN)
#define HEADS 8
#define NCLS 40
#define SLOPE 0.2f

#define SCAN_B 512
#define NBLK ((NN + SCAN_B - 1) / SCAN_B)   // 196

#define BW 512                    // dsts per bucket
#define NB ((NN + BW - 1) / BW)   // 196 buckets
#define EPB 8192                  // edges per bucket-pass block

typedef unsigned short ushort_t;
typedef __attribute__((ext_vector_type(8))) short short8;
typedef __attribute__((ext_vector_type(8))) _Float16 half8;
typedef __attribute__((ext_vector_type(4))) float f32x4;

static __device__ __forceinline__ ushort_t f2bf(float f) {
    unsigned u = __float_as_uint(f);
    unsigned r = (u + 0x7FFFu + ((u >> 16) & 1u)) >> 16;   // RNE
    return (ushort_t)r;
}
static __device__ __forceinline__ float bf2f(ushort_t b) {
    return __uint_as_float(((unsigned)b) << 16);
}
static __device__ __forceinline__ ushort_t f2h(float f) {
    _Float16 h = (_Float16)f;
    return __builtin_bit_cast(ushort_t, h);
}
static __device__ __forceinline__ float h2f(ushort_t u) {
    return (float)__builtin_bit_cast(_Float16, u);
}

// ----------------- CSR build -----------------
__global__ void k_init0(int* __restrict__ p, int n) {
    int i = blockIdx.x * blockDim.x + threadIdx.x;
    if (i < n) p[i] = 0;
}

__global__ void k_hist(const int* __restrict__ ei, int* __restrict__ deg) {
    int base = blockIdx.x * 1024 + threadIdx.x;
#pragma unroll
    for (int i = 0; i < 4; i++) {
        int e = base + i * 256;
        if (e < NE) {
            unsigned d = (unsigned)ei[NE + e];
            if (d < NN) atomicAdd(&deg[d], 1);   // fire-and-forget
        }
    }
}

__global__ void k_blocksum(const int* __restrict__ deg, int* __restrict__ degt,
                           int* __restrict__ bsum) {
    __shared__ int sh[SCAN_B];
    int b = blockIdx.x;
    int i = b * SCAN_B + threadIdx.x;
    int tot = 0;
    if (i < NN) {
        tot = 1 + deg[i];  // self loop
        degt[i] = tot;
    }
    sh[threadIdx.x] = tot;
    __syncthreads();
    for (int s = SCAN_B / 2; s > 0; s >>= 1) {
        if (threadIdx.x < s) sh[threadIdx.x] += sh[threadIdx.x + s];
        __syncthreads();
    }
    if (threadIdx.x == 0) bsum[b] = sh[0];
}

__global__ void k_scan_bsums(int* __restrict__ bsum, int nblk) {
    __shared__ int sh[1024];
    int t = threadIdx.x;
    int v = (t < nblk) ? bsum[t] : 0;
    sh[t] = v;
    __syncthreads();
    for (int o = 1; o < 1024; o <<= 1) {
        int add = (t >= o) ? sh[t - o] : 0;
        __syncthreads();
        sh[t] += add;
        __syncthreads();
    }
    if (t < nblk) bsum[t] = sh[t] - v;  // exclusive
}

__global__ void k_offsets(const int* __restrict__ degt, const int* __restrict__ bsum,
                          int* __restrict__ offset) {
    __shared__ int sh[SCAN_B];
    int b = blockIdx.x, t = threadIdx.x;
    int i = b * SCAN_B + t;
    int v = (i < NN) ? degt[i] : 0;
    sh[t] = v;
    __syncthreads();
    for (int o = 1; o < SCAN_B; o <<= 1) {
        int add = (t >= o) ? sh[t - o] : 0;
        __syncthreads();
        sh[t] += add;
        __syncthreads();
    }
    if (i < NN) offset[i] = sh[t] - v + bsum[b];
}

__global__ void k_initgcur(const int* __restrict__ offset, int* __restrict__ gcur) {
    int b = threadIdx.x;
    if (b < NB) gcur[b] = offset[b * BW];
}

// pass 1: partition edges into dst-range buckets, contiguous runs per block
__global__ __launch_bounds__(256) void k_bucket(const int* __restrict__ ei,
                                                int* __restrict__ gcur,
                                                uint2* __restrict__ ebuf) {
    __shared__ int cnt[NB];
    __shared__ int cnt2[NB];
    __shared__ int base[NB];
    int t = threadIdx.x;
    for (int b = t; b < NB; b += 256) { cnt[b] = 0; cnt2[b] = 0; }
    __syncthreads();
    int e0 = blockIdx.x * EPB;
#pragma unroll 4
    for (int i = 0; i < EPB / 256; i++) {
        int e = e0 + i * 256 + t;
        if (e < NE) {
            unsigned d = (unsigned)ei[NE + e];
            if (d < NN) atomicAdd(&cnt[d >> 9], 1);
        }
    }
    __syncthreads();
    for (int b = t; b < NB; b += 256) {
        base[b] = cnt[b] ? atomicAdd(&gcur[b], cnt[b]) : 0;
    }
    __syncthreads();
#pragma unroll 4
    for (int i = 0; i < EPB / 256; i++) {
        int e = e0 + i * 256 + t;
        if (e < NE) {
            unsigned d = (unsigned)ei[NE + e];
            unsigned s = (unsigned)ei[e];
            if (d < NN && s < NN) {
                int b = d >> 9;
                int r = atomicAdd(&cnt2[b], 1);
                ebuf[base[b] + r] = make_uint2(s, d);
            }
        }
    }
}

// pass 2: one block per bucket, LDS cursors, near-local csr writes
__global__ __launch_bounds__(256) void k_place(const int* __restrict__ offset,
                                               const int* __restrict__ gcur,
                                               const uint2* __restrict__ ebuf,
                                               int* __restrict__ csr_src) {
    __shared__ int lcur[BW];
    int b = blockIdx.x;
    int d0 = b * BW;
    int dN = (NN - d0 < BW) ? (NN - d0) : BW;
    int t = threadIdx.x;
    for (int i = t; i < dN; i += 256) {
        int o = offset[d0 + i];
        lcur[i] = o + 1;
        csr_src[o] = d0 + i;     // self loop
    }
    __syncthreads();
    int start = offset[d0];
    int endg = gcur[b];          // final cursor after pass 1
    for (int i = start + t; i < endg; i += 256) {
        uint2 e = ebuf[i];
        int pos = atomicAdd(&lcur[e.y - d0], 1);
        csr_src[pos] = (int)e.x;
    }
}

// ------- split W1 (bf16 hi/lo, [n][k]) + W2 (f16 hi/lo, padded [48][256]) --
__global__ void k_splitW(const float* __restrict__ W1, ushort_t* __restrict__ W1ht,
                         ushort_t* __restrict__ W1lt, const float* __restrict__ W2,
                         ushort_t* __restrict__ W2ht, ushort_t* __restrict__ W2lt) {
    if (blockIdx.x < 256) {
        int k = blockIdx.x, n = threadIdx.x;
        float v = W1[k * 256 + n];
        ushort_t hi = f2bf(v);
        ushort_t lo = f2bf(v - bf2f(hi));
        W1ht[n * 256 + k] = hi;
        W1lt[n * 256 + k] = lo;
    } else {
        int n = blockIdx.x - 256, k = threadIdx.x;
        float v = (n < NCLS) ? W2[k * NCLS + n] : 0.f;
        ushort_t hi = f2h(v);
        ushort_t lo = f2h(v - h2f(hi));
        W2ht[n * 256 + k] = hi;
        W2lt[n * 256 + k] = lo;
    }
}

// ----------------- GEMM1 (MFMA split-bf16): h1h(f16) = x @ W1; fused alphas
#define LSTR 40   // ushorts per LDS row
__global__ __launch_bounds__(256) void k_gemm1(const float* __restrict__ A,
                                               const ushort_t* __restrict__ Bht,
                                               const ushort_t* __restrict__ Blt,
                                               const float* __restrict__ attS,
                                               const float* __restrict__ attD,
                                               ushort_t* __restrict__ h1h,
                                               float* __restrict__ as1,
                                               float* __restrict__ ad1) {
    __shared__ ushort_t Ah[128 * LSTR];
    __shared__ ushort_t Al[128 * LSTR];
    __shared__ ushort_t Bh[128 * LSTR];
    __shared__ ushort_t Bl[128 * LSTR];

    int bx = blockIdx.x & 1;
    int by = blockIdx.x >> 1;
    int row0 = by * 128, col0 = bx * 128;
    int t = threadIdx.x;
    int w = t >> 6, lane = t & 63;
    int lr = lane & 15, lg = lane >> 4;
    int R0 = (w >> 1) * 64, C0 = (w & 1) * 64;

    int ar = t >> 1, ah = t & 1;          // A: row, k-half(16 f32)
    int gr_a = row0 + ar;

    f32x4 acc[4][4];
#pragma unroll
    for (int i = 0; i < 4; i++)
#pragma unroll
        for (int j = 0; j < 4; j++) acc[i][j] = (f32x4){0.f, 0.f, 0.f, 0.f};

    for (int it = 0; it < 8; it++) {
        int k0 = it * 32;
        __syncthreads();
        // ---- stage A (convert f32 -> bf16 hi/lo) ----
        {
            float f[16];
            if (gr_a < NN) {
                const float* ap = A + (size_t)gr_a * 256 + k0 + ah * 16;
#pragma unroll
                for (int i = 0; i < 4; i++) {
                    float4 v = *reinterpret_cast<const float4*>(ap + i * 4);
                    f[i * 4 + 0] = v.x; f[i * 4 + 1] = v.y; f[i * 4 + 2] = v.z; f[i * 4 + 3] = v.w;
                }
            } else {
#pragma unroll
                for (int i = 0; i < 16; i++) f[i] = 0.f;
            }
            unsigned hw[8], lw[8];
#pragma unroll
            for (int i = 0; i < 8; i++) {
                ushort_t h0 = f2bf(f[2 * i]), h1v = f2bf(f[2 * i + 1]);
                ushort_t l0 = f2bf(f[2 * i] - bf2f(h0)), l1 = f2bf(f[2 * i + 1] - bf2f(h1v));
                hw[i] = (unsigned)h0 | ((unsigned)h1v << 16);
                lw[i] = (unsigned)l0 | ((unsigned)l1 << 16);
            }
            uint4* dsth = reinterpret_cast<uint4*>(&Ah[ar * LSTR + ah * 16]);
            dsth[0] = make_uint4(hw[0], hw[1], hw[2], hw[3]);
            dsth[1] = make_uint4(hw[4], hw[5], hw[6], hw[7]);
            uint4* dstl = reinterpret_cast<uint4*>(&Al[ar * LSTR + ah * 16]);
            dstl[0] = make_uint4(lw[0], lw[1], lw[2], lw[3]);
            dstl[1] = make_uint4(lw[4], lw[5], lw[6], lw[7]);
        }
        // ---- stage B (pre-split, pre-transposed [n][k]) ----
        {
            int bn = t >> 1, bh2 = t & 1;
            const uint4* sh = reinterpret_cast<const uint4*>(Bht + (size_t)(col0 + bn) * 256 + k0 + bh2 * 16);
            const uint4* sl = reinterpret_cast<const uint4*>(Blt + (size_t)(col0 + bn) * 256 + k0 + bh2 * 16);
            uint4* dh = reinterpret_cast<uint4*>(&Bh[bn * LSTR + bh2 * 16]);
            uint4* dl = reinterpret_cast<uint4*>(&Bl[bn * LSTR + bh2 * 16]);
            dh[0] = sh[0]; dh[1] = sh[1];
            dl[0] = sl[0]; dl[1] = sl[1];
        }
        __syncthreads();
        // ---- fragments + MFMA ----
        short8 bhf[4], blf[4];
#pragma unroll
        for (int ni = 0; ni < 4; ni++) {
            int c = C0 + ni * 16 + lr;
            bhf[ni] = *reinterpret_cast<const short8*>(&Bh[c * LSTR + lg * 8]);
            blf[ni] = *reinterpret_cast<const short8*>(&Bl[c * LSTR + lg * 8]);
        }
#pragma unroll
        for (int mi = 0; mi < 4; mi++) {
            int r = R0 + mi * 16 + lr;
            short8 ahf = *reinterpret_cast<const short8*>(&Ah[r * LSTR + lg * 8]);
            short8 alf = *reinterpret_cast<const short8*>(&Al[r * LSTR + lg * 8]);
#pragma unroll
            for (int ni = 0; ni < 4; ni++) {
                acc[mi][ni] = __builtin_amdgcn_mfma_f32_16x16x32_bf16(ahf, bhf[ni], acc[mi][ni], 0, 0, 0);
                acc[mi][ni] = __builtin_amdgcn_mfma_f32_16x16x32_bf16(alf, bhf[ni], acc[mi][ni], 0, 0, 0);
                acc[mi][ni] = __builtin_amdgcn_mfma_f32_16x16x32_bf16(ahf, blf[ni], acc[mi][ni], 0, 0, 0);
            }
        }
    }

    // ---- epilogue: f16 store + fused alpha dots ----
    int cn[4];
    float sa[4], da[4];
#pragma unroll
    for (int ni = 0; ni < 4; ni++) {
        cn[ni] = col0 + C0 + ni * 16 + lr;
        sa[ni] = attS[cn[ni]];
        da[ni] = attD[cn[ni]];
    }
    int head0 = (col0 + C0) >> 5;
#pragma unroll
    for (int mi = 0; mi < 4; mi++) {
#pragma unroll
        for (int r = 0; r < 4; r++) {
            int gr = row0 + R0 + mi * 16 + lg * 4 + r;
            float v0 = acc[mi][0][r], v1 = acc[mi][1][r];
            float v2 = acc[mi][2][r], v3 = acc[mi][3][r];
            float ps0 = v0 * sa[0] + v1 * sa[1];
            float pd0 = v0 * da[0] + v1 * da[1];
            float ps1 = v2 * sa[2] + v3 * sa[3];
            float pd1 = v2 * da[2] + v3 * da[3];
#pragma unroll
            for (int m = 1; m <= 8; m <<= 1) {
                ps0 += __shfl_xor(ps0, m);
                pd0 += __shfl_xor(pd0, m);
                ps1 += __shfl_xor(ps1, m);
                pd1 += __shfl_xor(pd1, m);
            }
            if (gr < NN) {
                if (lr == 0) {
                    as1[gr * 8 + head0] = ps0;
                    ad1[gr * 8 + head0] = pd0;
                    as1[gr * 8 + head0 + 1] = ps1;
                    ad1[gr * 8 + head0 + 1] = pd1;
                }
                ushort_t* hp = h1h + (size_t)gr * 256;
                hp[cn[0]] = f2h(v0);
                hp[cn[1]] = f2h(v1);
                hp[cn[2]] = f2h(v2);
                hp[cn[3]] = f2h(v3);
            }
        }
    }
}

// ------- softmax stats + f16 weight write, layer 1: one wave/node ----------
__global__ __launch_bounds__(256) void k_soft1(const int* __restrict__ csr_src,
                                               const int* __restrict__ offset,
                                               const int* __restrict__ degt,
                                               const float* __restrict__ as1,
                                               const float* __restrict__ ad1,
                                               ushort_t* __restrict__ w1h) {
    int wave = (blockIdx.x * blockDim.x + threadIdx.x) >> 6;
    int lane = threadIdx.x & 63;
    if (wave >= NN) return;
    int d = wave;
    int sub = lane >> 3, h = lane & 7;
    float ad = ad1[d * 8 + h];
    int beg = offset[d], cnt = degt[d];
    float m = -1e30f, s = 0.f;
    for (int j = sub; j < cnt; j += 8) {
        int src = csr_src[beg + j];
        float e = as1[src * 8 + h] + ad;
        e = (e > 0.f) ? e : SLOPE * e;
        float mn = fmaxf(m, e);
        s = s * __expf(m - mn) + __expf(e - mn);
        m = mn;
    }
#pragma unroll
    for (int mask = 8; mask <= 32; mask <<= 1) {
        float mo = __shfl_xor(m, mask);
        float so = __shfl_xor(s, mask);
        float mn = fmaxf(m, mo);
        s = s * __expf(m - mn) + so * __expf(mo - mn);
        m = mn;
    }
    float di = 1.f / (s + 1e-16f);
    for (int j = sub; j < cnt; j += 8) {
        int src = csr_src[beg + j];
        float e = as1[src * 8 + h] + ad;
        e = (e > 0.f) ? e : SLOPE * e;
        w1h[(size_t)(beg + j) * 8 + h] = f2h(__expf(e - m) * di);
    }
}

// ------- aggregate pass, layer 1: one wave/node (R8 structure, f16 w) ------
__global__ __launch_bounds__(256) void k_agg1(const int* __restrict__ csr_src,
                                              const int* __restrict__ offset,
                                              const int* __restrict__ degt,
                                              const ushort_t* __restrict__ h1h,
                                              const ushort_t* __restrict__ w1h,
                                              const float* __restrict__ bias1,
                                              ushort_t* __restrict__ h2h) {
    int wave = (blockIdx.x * blockDim.x + threadIdx.x) >> 6;
    int lane = threadIdx.x & 63;
    if (wave >= NN) return;
    int d = wave;
    int h = lane >> 3;
    int f0 = lane * 4;
    int beg = offset[d], cnt = degt[d];
    float ax = 0.f, ay = 0.f, az = 0.f, aw = 0.f;
#pragma unroll 4
    for (int j = 0; j < cnt; j++) {
        int s = csr_src[beg + j];
        float wg = h2f(w1h[(size_t)(beg + j) * 8 + h]);
        ushort4 hv = *reinterpret_cast<const ushort4*>(h1h + (size_t)s * 256 + f0);
        ax += wg * (float)__builtin_bit_cast(_Float16, hv.x);
        ay += wg * (float)__builtin_bit_cast(_Float16, hv.y);
        az += wg * (float)__builtin_bit_cast(_Float16, hv.z);
        aw += wg * (float)__builtin_bit_cast(_Float16, hv.w);
    }
    float4 b = *reinterpret_cast<const float4*>(bias1 + f0);
    float vx = ax + b.x;
    float vy = ay + b.y;
    float vz = az + b.z;
    float vw = aw + b.w;
    vx = (vx > 0.f) ? vx : expm1f(vx);
    vy = (vy > 0.f) ? vy : expm1f(vy);
    vz = (vz > 0.f) ? vz : expm1f(vz);
    vw = (vw > 0.f) ? vw : expm1f(vw);
    ushort4 o;
    o.x = f2h(vx); o.y = f2h(vy); o.z = f2h(vz); o.w = f2h(vw);
    *reinterpret_cast<ushort4*>(h2h + (size_t)d * 256 + f0) = o;
}

// ----------------- GEMM2 (MFMA f16): hh(f16) = h2h @ W2; fused alpha2 ------
__global__ __launch_bounds__(256) void k_gemm2(const ushort_t* __restrict__ A,
                                               const ushort_t* __restrict__ Bht,
                                               const ushort_t* __restrict__ Blt,
                                               const float* __restrict__ attS,
                                               const float* __restrict__ attD,
                                               ushort_t* __restrict__ hh,
                                               float* __restrict__ as2,
                                               float* __restrict__ ad2) {
    __shared__ ushort_t Ash[128 * LSTR];
    __shared__ ushort_t Bh[48 * LSTR];
    __shared__ ushort_t Bl[48 * LSTR];
    int row0 = blockIdx.x * 128;
    int t = threadIdx.x;
    int w = t >> 6, lane = t & 63;
    int lr = lane & 15, lg = lane >> 4;
    int R0 = w * 32;

    f32x4 acc[2][3];
#pragma unroll
    for (int i = 0; i < 2; i++)
#pragma unroll
        for (int j = 0; j < 3; j++) acc[i][j] = (f32x4){0.f, 0.f, 0.f, 0.f};

    for (int it = 0; it < 8; it++) {
        int k0 = it * 32;
        __syncthreads();
#pragma unroll
        for (int i = 0; i < 2; i++) {
            int chunk = t + i * 256;
            int r = chunk >> 2, part = chunk & 3;
            int gr = row0 + r;
            uint4 v = make_uint4(0u, 0u, 0u, 0u);
            if (gr < NN) v = *reinterpret_cast<const uint4*>(A + (size_t)gr * 256 + k0 + part * 8);
            *reinterpret_cast<uint4*>(&Ash[r * LSTR + part * 8]) = v;
        }
        if (t < 192) {
            int bn = t >> 2, part = t & 3;
            *reinterpret_cast<uint4*>(&Bh[bn * LSTR + part * 8]) =
                *reinterpret_cast<const uint4*>(Bht + (size_t)bn * 256 + k0 + part * 8);
            *reinterpret_cast<uint4*>(&Bl[bn * LSTR + part * 8]) =
                *reinterpret_cast<const uint4*>(Blt + (size_t)bn * 256 + k0 + part * 8);
        }
        __syncthreads();
        half8 bhf[3], blf[3];
#pragma unroll
        for (int ni = 0; ni < 3; ni++) {
            int c = ni * 16 + lr;
            bhf[ni] = *reinterpret_cast<const half8*>(&Bh[c * LSTR + lg * 8]);
            blf[ni] = *reinterpret_cast<const half8*>(&Bl[c * LSTR + lg * 8]);
        }
#pragma unroll
        for (int mi = 0; mi < 2; mi++) {
            int r = R0 + mi * 16 + lr;
            half8 af = *reinterpret_cast<const half8*>(&Ash[r * LSTR + lg * 8]);
#pragma unroll
            for (int ni = 0; ni < 3; ni++) {
                acc[mi][ni] = __builtin_amdgcn_mfma_f32_16x16x32_f16(af, bhf[ni], acc[mi][ni], 0, 0, 0);
                acc[mi][ni] = __builtin_amdgcn_mfma_f32_16x16x32_f16(af, blf[ni], acc[mi][ni], 0, 0, 0);
            }
        }
    }

    int cn[3];
    float sa[3], da[3];
#pragma unroll
    for (int ni = 0; ni < 3; ni++) {
        cn[ni] = ni * 16 + lr;
        sa[ni] = (cn[ni] < NCLS) ? attS[cn[ni]] : 0.f;
        da[ni] = (cn[ni] < NCLS) ? attD[cn[ni]] : 0.f;
    }
#pragma unroll
    for (int mi = 0; mi < 2; mi++) {
#pragma unroll
        for (int r = 0; r < 4; r++) {
            int gr = row0 + R0 + mi * 16 + lg * 4 + r;
            float v0 = acc[mi][0][r], v1 = acc[mi][1][r], v2 = acc[mi][2][r];
            float ps = v0 * sa[0] + v1 * sa[1] + v2 * sa[2];
            float pd = v0 * da[0] + v1 * da[1] + v2 * da[2];
#pragma unroll
            for (int m = 1; m <= 8; m <<= 1) {
                ps += __shfl_xor(ps, m);
                pd += __shfl_xor(pd, m);
            }
            if (gr < NN) {
                if (lr == 0) { as2[gr] = ps; ad2[gr] = pd; }
                ushort_t* hp = hh + (size_t)gr * NCLS;
                if (cn[0] < NCLS) hp[cn[0]] = f2h(v0);
                if (cn[1] < NCLS) hp[cn[1]] = f2h(v1);
                if (cn[2] < NCLS) hp[cn[2]] = f2h(v2);
            }
        }
    }
}

// ------- softmax stats + f16 weight write, layer 2: one wave/node ----------
__global__ __launch_bounds__(256) void k_soft2(const int* __restrict__ csr_src,
                                               const int* __restrict__ offset,
                                               const int* __restrict__ degt,
                                               const float* __restrict__ as2,
                                               const float* __restrict__ ad2,
                                               ushort_t* __restrict__ w2h) {
    int wave = (blockIdx.x * blockDim.x + threadIdx.x) >> 6;
    int lane = threadIdx.x & 63;
    if (wave >= NN) return;
    int d = wave;
    float ad = ad2[d];
    int beg = offset[d], cnt = degt[d];
    float m = -1e30f, s = 0.f;
    for (int j = lane; j < cnt; j += 64) {
        int src = csr_src[beg + j];
        float e = as2[src] + ad;
        e = (e > 0.f) ? e : SLOPE * e;
        float mn = fmaxf(m, e);
        s = s * __expf(m - mn) + __expf(e - mn);
        m = mn;
    }
#pragma unroll
    for (int mask = 1; mask <= 32; mask <<= 1) {
        float mo = __shfl_xor(m, mask);
        float so = __shfl_xor(s, mask);
        float mn = fmaxf(m, mo);
        s = s * __expf(m - mn) + so * __expf(mo - mn);
        m = mn;
    }
    float di = 1.f / (s + 1e-16f);
    for (int j = lane; j < cnt; j += 64) {
        int src = csr_src[beg + j];
        float e = as2[src] + ad;
        e = (e > 0.f) ? e : SLOPE * e;
        w2h[beg + j] = f2h(__expf(e - m) * di);
    }
}

// ------- aggregate pass, layer 2: 3 edges in flight, 20 lanes each ---------
__global__ __launch_bounds__(256) void k_agg2(const int* __restrict__ csr_src,
                                              const int* __restrict__ offset,
                                              const int* __restrict__ degt,
                                              const ushort_t* __restrict__ hh,
                                              const ushort_t* __restrict__ w2h,
                                              const float* __restrict__ bias2,
                                              float* __restrict__ out) {
    int wave = (blockIdx.x * blockDim.x + threadIdx.x) >> 6;
    int lane = threadIdx.x & 63;
    if (wave >= NN) return;
    int d = wave;
    int es = lane / 20;       // edge slot 0..2 (3 = idle)
    int ch = lane % 20;       // uint chunk -> classes 2ch, 2ch+1
    int beg = offset[d], cnt = degt[d];
    float a0 = 0.f, a1 = 0.f;
    for (int j0 = 0; j0 < cnt; j0 += 3) {
        int j = j0 + es;
        if (es < 3 && j < cnt) {
            int s = csr_src[beg + j];
            float w = h2f(w2h[beg + j]);
            unsigned v = *reinterpret_cast<const unsigned*>(hh + (size_t)s * NCLS + ch * 2);
            a0 += w * (float)__builtin_bit_cast(_Float16, (ushort_t)(v & 0xFFFFu));
            a1 += w * (float)__builtin_bit_cast(_Float16, (ushort_t)(v >> 16));
        }
    }
    float t0 = __shfl(a0, lane + 20);
    float t1 = __shfl(a0, lane + 40);
    float u0 = __shfl(a1, lane + 20);
    float u1 = __shfl(a1, lane + 40);
    if (lane < 20) {
        float2 o;
        o.x = a0 + t0 + t1 + bias2[ch * 2];
        o.y = a1 + u0 + u1 + bias2[ch * 2 + 1];
        *reinterpret_cast<float2*>(out + (size_t)d * NCLS + ch * 2) = o;
    }
}

extern "C" void kernel_launch(void* const* d_in, const int* in_sizes, int n_in,
                              void* d_out, int out_size, void* d_ws, size_t ws_size,
                              hipStream_t stream) {
    const float* x      = (const float*)d_in[0];
    const int* ei       = (const int*)d_in[1];   // int64 in ref -> int32 on device
    const float* W1     = (const float*)d_in[2];
    const float* att_s1 = (const float*)d_in[3];
    const float* att_d1 = (const float*)d_in[4];
    const float* bias1  = (const float*)d_in[5];
    const float* W2     = (const float*)d_in[6];
    const float* att_s2 = (const float*)d_in[7];
    const float* att_d2 = (const float*)d_in[8];
    const float* bias2  = (const float*)d_in[9];
    float* out = (float*)d_out;

    char* ws = (char*)d_ws;
    size_t off = 0;
    auto alloc = [&](size_t bytes) -> void* {
        void* p = ws + off;
        off = (off + bytes + 255) & ~(size_t)255;
        return p;
    };
    ushort_t* h1h = (ushort_t*)alloc((size_t)NN * 256 * 2);
    ushort_t* h2h = (ushort_t*)alloc((size_t)NN * 256 * 2);
    ushort_t* hh  = (ushort_t*)alloc((size_t)NN * NCLS * 2);
    float* as1  = (float*)alloc((size_t)NN * 8 * 4);
    float* ad1  = (float*)alloc((size_t)NN * 8 * 4);
    float* as2  = (float*)alloc((size_t)NN * 4);
    float* ad2  = (float*)alloc((size_t)NN * 4);
    ushort_t* w1h = (ushort_t*)alloc((size_t)ETOT * 8 * 2);
    ushort_t* w2h = (ushort_t*)alloc((size_t)ETOT * 2);
    int* deg    = (int*)alloc((size_t)NN * 4);
    int* degt   = (int*)alloc((size_t)NN * 4);
    int* offs   = (int*)alloc((size_t)(NN + 1) * 4);
    int* csr    = (int*)alloc((size_t)ETOT * 4);
    uint2* ebuf = (uint2*)alloc((size_t)ETOT * 8);
    int* gcur   = (int*)alloc((size_t)NB * 4 + 256);
    int* bsum   = (int*)alloc(4096);
    ushort_t* W1ht = (ushort_t*)alloc((size_t)256 * 256 * 2);
    ushort_t* W1lt = (ushort_t*)alloc((size_t)256 * 256 * 2);
    ushort_t* W2ht = (ushort_t*)alloc((size_t)48 * 256 * 2);
    ushort_t* W2lt = (ushort_t*)alloc((size_t)48 * 256 * 2);

    // CSR build: hist -> scan -> bucket -> place
    k_init0<<<(NN + 255) / 256, 256, 0, stream>>>(deg, NN);
    k_hist<<<(NE + 1023) / 1024, 256, 0, stream>>>(ei, deg);
    k_blocksum<<<NBLK, SCAN_B, 0, stream>>>(deg, degt, bsum);
    k_scan_bsums<<<1, 1024, 0, stream>>>(bsum, NBLK);
    k_offsets<<<NBLK, SCAN_B, 0, stream>>>(degt, bsum, offs);
    k_initgcur<<<1, 256, 0, stream>>>(offs, gcur);
    k_bucket<<<(NE + EPB - 1) / EPB, 256, 0, stream>>>(ei, gcur, ebuf);
    k_place<<<NB, 256, 0, stream>>>(offs, gcur, ebuf, csr);

    // Layer 1
    k_splitW<<<304, 256, 0, stream>>>(W1, W1ht, W1lt, W2, W2ht, W2lt);
    k_gemm1<<<((NN + 127) / 128) * 2, 256, 0, stream>>>(x, W1ht, W1lt, att_s1, att_d1, h1h, as1, ad1);
    k_soft1<<<(NN + 3) / 4, 256, 0, stream>>>(csr, offs, degt, as1, ad1, w1h);
    k_agg1<<<(NN + 3) / 4, 256, 0, stream>>>(csr, offs, degt, h1h, w1h, bias1, h2h);

    // Layer 2
    k_gemm2<<<(NN + 127) / 128, 256, 0, stream>>>(h2h, W2ht, W2lt, att_s2, att_d2, hh, as2, ad2);
    k_soft2<<<(NN + 3) / 4, 256, 0, stream>>>(csr, offs, degt, as2, ad2, w2h);
    k_agg2<<<(NN + 3) / 4, 256, 0, stream>>>(csr, offs, degt, hh, w2h, bias2, out);
}